// Round 9
// baseline (5095.369 us; speedup 1.0000x reference)
//
#include <hip/hip_runtime.h>
#include <math.h>

#define BB 8
#define NN 8192
#define SS 2048
#define KK 32
#define NP (BB*SS*KK)   /* 524288 points through the MLP */
#define EPSF 1e-5f

// ---------------------------------------------------------------------------
// DPP-based wave64 max of a u64 key. Pure VALU. Valid in lane 63.
// ---------------------------------------------------------------------------
template <int CTRL>
__device__ __forceinline__ unsigned long long dpp_max_step(unsigned long long key) {
    unsigned lo = (unsigned)key, hi = (unsigned)(key >> 32);
    unsigned nlo = (unsigned)__builtin_amdgcn_update_dpp((int)lo, (int)lo, CTRL, 0xf, 0xf, false);
    unsigned nhi = (unsigned)__builtin_amdgcn_update_dpp((int)hi, (int)hi, CTRL, 0xf, 0xf, false);
    unsigned long long nk = ((unsigned long long)nhi << 32) | nlo;
    return nk > key ? nk : key;
}

__device__ __forceinline__ unsigned long long wave_max_u64(unsigned long long key) {
    key = dpp_max_step<0x111>(key);  // row_shr:1
    key = dpp_max_step<0x112>(key);  // row_shr:2
    key = dpp_max_step<0x114>(key);  // row_shr:4
    key = dpp_max_step<0x118>(key);  // row_shr:8
    key = dpp_max_step<0x142>(key);  // row_bcast:15
    key = dpp_max_step<0x143>(key);  // row_bcast:31
    return key;
}

// ---------------------------------------------------------------------------
// Bucket-FPS: one block (256 thr) per batch. Prologue counting-sorts points
// into an 8x8x8 grid (LDS SoA sx/sy/sz + u16 orig-idx map); 128 tiles of 64
// sorted points w/ tight bboxes. Per iteration:
//   P1: lane<32 tests own tile: skip iff d_min(c,bbox) >= tile_max.
//       (RN rounding is monotone -> computed d_min <= every point's computed
//        d -> skipped tiles' dist/min are bit-exact unchanged.)
//   P2: dirty tiles only: update LDS dist, reduce tile (max, tie-key) via DPP.
//   P3: every wave redundantly maxes all 128 tile keys (1 ds_read_b128/lane)
//       -> argmax; tie-break by ORIGINAL index (np.argmax semantics) via
//       key = dist<<32 | (8191-orig)<<13 | sorted_pos.
// min is exactly associative; d uses the reference __f*_rn chain; coords are
// exact copies -> bit-identical FPS sequence.
// ---------------------------------------------------------------------------
__global__ __launch_bounds__(256) void fps_kernel(const float* __restrict__ xyz,
                                                  float* __restrict__ out_newxyz) {
#pragma clang fp contract(off)
    int b = blockIdx.x;
    int t = threadIdx.x;
    int wid  = t >> 6;               // 0..3
    int lane = t & 63;
    const float* x = xyz + b * NN * 3;
    float* nout = out_newxyz + b * SS * 3;

    __shared__ float sx[NN], sy[NN], sz[NN];          // 96 KB sorted coords
    __shared__ unsigned short sidx[NN];               // 16 KB orig index
    __shared__ float sdist[NN];                       // 32 KB min-dist
    __shared__ float tbox[128][6];                    // tile bbox (tight)
    __shared__ __align__(16) unsigned long long tkey[128];  // (max, tie) keys
    __shared__ int cellstart[512];                    // hist -> prefix -> cursor
    __shared__ float red[4][6];                       // block bbox scratch
    __shared__ int spos0;                             // sorted pos of orig pt 0

    // ---- prologue: batch bbox ----
    float mnx = 1e30f, mxx = -1e30f, mny = 1e30f, mxy = -1e30f, mnz = 1e30f, mxz = -1e30f;
    for (int i = 0; i < NN / 256; i++) {
        int p = t + i * 256;
        float px = x[p * 3 + 0], py = x[p * 3 + 1], pz = x[p * 3 + 2];
        mnx = fminf(mnx, px); mxx = fmaxf(mxx, px);
        mny = fminf(mny, py); mxy = fmaxf(mxy, py);
        mnz = fminf(mnz, pz); mxz = fmaxf(mxz, pz);
    }
#pragma unroll
    for (int off = 1; off < 64; off <<= 1) {
        mnx = fminf(mnx, __shfl_xor(mnx, off)); mxx = fmaxf(mxx, __shfl_xor(mxx, off));
        mny = fminf(mny, __shfl_xor(mny, off)); mxy = fmaxf(mxy, __shfl_xor(mxy, off));
        mnz = fminf(mnz, __shfl_xor(mnz, off)); mxz = fmaxf(mxz, __shfl_xor(mxz, off));
    }
    if (lane == 0) {
        red[wid][0] = mnx; red[wid][1] = mxx; red[wid][2] = mny;
        red[wid][3] = mxy; red[wid][4] = mnz; red[wid][5] = mxz;
    }
    __syncthreads();
    mnx = fminf(fminf(red[0][0], red[1][0]), fminf(red[2][0], red[3][0]));
    mxx = fmaxf(fmaxf(red[0][1], red[1][1]), fmaxf(red[2][1], red[3][1]));
    mny = fminf(fminf(red[0][2], red[1][2]), fminf(red[2][2], red[3][2]));
    mxy = fmaxf(fmaxf(red[0][3], red[1][3]), fmaxf(red[2][3], red[3][3]));
    mnz = fminf(fminf(red[0][4], red[1][4]), fminf(red[2][4], red[3][4]));
    mxz = fmaxf(fmaxf(red[0][5], red[1][5]), fmaxf(red[2][5], red[3][5]));
    float sclx = 8.0f / (mxx - mnx), scly = 8.0f / (mxy - mny), sclz = 8.0f / (mxz - mnz);

    // ---- histogram ----
    cellstart[t] = 0; cellstart[t + 256] = 0;
    __syncthreads();
    for (int i = 0; i < NN / 256; i++) {
        int p = t + i * 256;
        float px = x[p * 3 + 0], py = x[p * 3 + 1], pz = x[p * 3 + 2];
        int ix = min(7, max(0, (int)((px - mnx) * sclx)));
        int iy = min(7, max(0, (int)((py - mny) * scly)));
        int iz = min(7, max(0, (int)((pz - mnz) * sclz)));
        atomicAdd(&cellstart[(iz * 8 + iy) * 8 + ix], 1);
    }
    __syncthreads();
    if (t == 0) {                                      // serial exclusive prefix
        int run = 0;
        for (int c2 = 0; c2 < 512; c2++) { int v = cellstart[c2]; cellstart[c2] = run; run += v; }
    }
    __syncthreads();
    // ---- scatter (sort) + dist init ----
    for (int i = 0; i < NN / 256; i++) {
        int p = t + i * 256;
        float px = x[p * 3 + 0], py = x[p * 3 + 1], pz = x[p * 3 + 2];
        int ix = min(7, max(0, (int)((px - mnx) * sclx)));
        int iy = min(7, max(0, (int)((py - mny) * scly)));
        int iz = min(7, max(0, (int)((pz - mnz) * sclz)));
        int pos = atomicAdd(&cellstart[(iz * 8 + iy) * 8 + ix], 1);
        sx[pos] = px; sy[pos] = py; sz[pos] = pz;
        sidx[pos] = (unsigned short)p;
        if (p == 0) spos0 = pos;
        sdist[p] = 1e10f;
    }
    if (t < 128) tkey[t] = ((unsigned long long)__float_as_uint(1e10f)) << 32;
    __syncthreads();
    // ---- tile bboxes (tight) ----
    for (int tt = 0; tt < 32; tt++) {
        int tile = wid * 32 + tt;
        int q = tile * 64 + lane;
        float vx = sx[q], vy = sy[q], vz = sz[q];
        float ax = vx, bx2 = vx, ay = vy, by2 = vy, az = vz, bz2 = vz;
#pragma unroll
        for (int off = 1; off < 64; off <<= 1) {
            ax = fminf(ax, __shfl_xor(ax, off)); bx2 = fmaxf(bx2, __shfl_xor(bx2, off));
            ay = fminf(ay, __shfl_xor(ay, off)); by2 = fmaxf(by2, __shfl_xor(by2, off));
            az = fminf(az, __shfl_xor(az, off)); bz2 = fmaxf(bz2, __shfl_xor(bz2, off));
        }
        if (lane == 0) {
            tbox[tile][0] = ax; tbox[tile][1] = bx2; tbox[tile][2] = ay;
            tbox[tile][3] = by2; tbox[tile][4] = az; tbox[tile][5] = bz2;
        }
    }
    __syncthreads();

    int sc = spos0;                                    // first centroid = orig pt 0
    float cx = sx[sc], cy = sy[sc], cz = sz[sc];

    for (int it = 0; it < SS; it++) {
        if (t == 0) {
            nout[it * 3 + 0] = cx;
            nout[it * 3 + 1] = cy;
            nout[it * 3 + 2] = cz;
        }
        // P1: bbox lower-bound test (lanes 0..31, one tile each)
        bool dirty = false;
        if (lane < 32) {
            int tile = wid * 32 + lane;
            float t1 = __fsub_rn(tbox[tile][0], cx);
            float t2 = __fsub_rn(cx, tbox[tile][1]);
            float tx = fmaxf(fmaxf(t1, t2), 0.f);
            t1 = __fsub_rn(tbox[tile][2], cy);
            t2 = __fsub_rn(cy, tbox[tile][3]);
            float ty = fmaxf(fmaxf(t1, t2), 0.f);
            t1 = __fsub_rn(tbox[tile][4], cz);
            t2 = __fsub_rn(cz, tbox[tile][5]);
            float tz = fmaxf(fmaxf(t1, t2), 0.f);
            float dmin = __fadd_rn(__fadd_rn(__fmul_rn(tx, tx), __fmul_rn(ty, ty)),
                                   __fmul_rn(tz, tz));
            float tmax = __uint_as_float((unsigned)(tkey[tile] >> 32));
            dirty = dmin < tmax;                        // else: no point can update
        }
        unsigned long long m = __ballot(dirty);
        // P2: update dirty tiles (whole wave per tile)
        while (m) {
            int bb = __ffsll(m) - 1;
            m &= m - 1;
            int tile = wid * 32 + bb;
            int q = tile * 64 + lane;
            float dx = __fsub_rn(sx[q], cx);
            float dy = __fsub_rn(sy[q], cy);
            float dz = __fsub_rn(sz[q], cz);
            float d  = __fadd_rn(__fadd_rn(__fmul_rn(dx, dx), __fmul_rn(dy, dy)),
                                 __fmul_rn(dz, dz));
            float e = fminf(sdist[q], d);
            sdist[q] = e;
            unsigned orig = sidx[q];
            unsigned long long key = ((unsigned long long)__float_as_uint(e) << 32)
                                   | ((8191u - orig) << 13) | (unsigned)q;
            key = wave_max_u64(key);
            if (lane == 63) tkey[tile] = key;
        }
        __syncthreads();
        // P3: every wave maxes all 128 keys (redundant, no exchange)
        ulonglong2 kp = *(const ulonglong2*)&tkey[lane * 2];
        unsigned long long k = kp.x > kp.y ? kp.x : kp.y;
        k = wave_max_u64(k);
        k = __shfl(k, 63);
        __syncthreads();                               // tkey reads done before next P2
        int gs = (int)((unsigned)k & 0x1FFFu);
        cx = sx[gs]; cy = sy[gs]; cz = sz[gs];
    }
}

// ---------------------------------------------------------------------------
// Ball query: one wave per query. Ordered compaction of first 32 in-radius
// indices (== reference's where->sort->truncate), pad with first index.
// ---------------------------------------------------------------------------
__global__ __launch_bounds__(256) void ballq_kernel(const float* __restrict__ xyz,
                                                    const float* __restrict__ new_xyz,
                                                    int* __restrict__ idx_out) {
    int q    = blockIdx.x * 4 + (threadIdx.x >> 6);
    int lane = threadIdx.x & 63;
    int b    = q >> 11;                        // q / SS
    const float* x = xyz + b * NN * 3;
    const float* c = new_xyz + q * 3;
    float cx = c[0], cy = c[1], cz = c[2];
    int* out = idx_out + q * KK;
    const float R2 = (float)(0.2 * 0.2);       // match reference double->f32 cast

    int count = 0;
    int first = -1;
    for (int base = 0; base < NN; base += 64) {
        int p = base + lane;
        float dx = __fsub_rn(x[p * 3 + 0], cx);
        float dy = __fsub_rn(x[p * 3 + 1], cy);
        float dz = __fsub_rn(x[p * 3 + 2], cz);
        float d  = __fadd_rn(__fadd_rn(__fmul_rn(dx, dx), __fmul_rn(dy, dy)),
                             __fmul_rn(dz, dz));
        bool in = !(d > R2);
        unsigned long long m = __ballot(in);
        if (first < 0 && m != 0ull) first = base + __ffsll((unsigned long long)m) - 1;
        int pre = __popcll(m & ((1ull << lane) - 1ull));
        int pos = count + pre;
        if (in && pos < KK) out[pos] = p;
        count += __popcll(m);
        if (count >= KK) break;                 // wave-uniform
    }
    for (int i2 = count + lane; i2 < KK; i2 += 64) out[i2] = first;
}

// ---------------------------------------------------------------------------
// MLP helpers (thread-per-point recompute chain; weights via uniform s_loads)
// ---------------------------------------------------------------------------
__device__ __forceinline__ void load_in6(const float* __restrict__ xyz,
                                         const float* __restrict__ points,
                                         const float* __restrict__ new_xyz,
                                         const int* __restrict__ idx, int p, float inx[6]) {
    int bs = p >> 5;
    int b  = bs >> 11;
    int pt = idx[p];
    const float* xb = xyz + ((long)b * NN + pt) * 3;
    const float* pb = points + ((long)b * NN + pt) * 3;
    const float* nx = new_xyz + bs * 3;
    inx[0] = xb[0] - nx[0];
    inx[1] = xb[1] - nx[1];
    inx[2] = xb[2] - nx[2];
    inx[3] = pb[0];
    inx[4] = pb[1];
    inx[5] = pb[2];
}

template <int CIN, int COUT>
__device__ __forceinline__ void linear(const float* __restrict__ w,
                                       const float* __restrict__ bias,
                                       const float* xin, float* yout) {
#pragma unroll
    for (int o = 0; o < COUT; o++) {
        float acc = bias[o];
#pragma unroll
        for (int j = 0; j < CIN; j++) acc = fmaf(w[o * CIN + j], xin[j], acc);
        yout[o] = acc;
    }
}

// compute per-channel BN scale/shift from raw sums (threads 0..C-1)
template <int C>
__device__ __forceinline__ void bn_coef(const float* __restrict__ stats,
                                        const float* __restrict__ g,
                                        const float* __restrict__ be,
                                        float* s_sc, float* s_sh) {
    int t = threadIdx.x;
    if (t < C) {
        float mean = stats[t] * (1.0f / (float)NP);
        float var  = stats[C + t] * (1.0f / (float)NP) - mean * mean;
        float rstd = 1.0f / sqrtf(var + EPSF);
        float sc = g[t] * rstd;
        s_sc[t] = sc;
        s_sh[t] = be[t] - mean * sc;
    }
    __syncthreads();
}

// block-level channel sums via LDS transpose (33.8KB), one atomic/chan/block
template <int C>
__device__ __forceinline__ void accum_stats(const float* y, float* __restrict__ gstats) {
    __shared__ float buf[256][33];
    int t = threadIdx.x;
#pragma unroll
    for (int h = 0; h < C / 32; h++) {
        __syncthreads();
#pragma unroll
        for (int c = 0; c < 32; c++) buf[t][c] = y[h * 32 + c];
        __syncthreads();
        if (t < 32) {
            float s = 0.f, sq = 0.f;
            for (int r = 0; r < 256; r++) {
                float v = buf[r][t];
                s += v;
                sq = fmaf(v, v, sq);
            }
            atomicAdd(&gstats[h * 32 + t], s);
            atomicAdd(&gstats[C + h * 32 + t], sq);
        }
    }
}

__global__ __launch_bounds__(256) void l0_stats_kernel(
    const float* __restrict__ xyz, const float* __restrict__ points,
    const float* __restrict__ new_xyz, const int* __restrict__ idx,
    const float* __restrict__ w0, const float* __restrict__ b0_,
    float* __restrict__ stats0) {
    int p = blockIdx.x * 256 + threadIdx.x;
    float inx[6];
    load_in6(xyz, points, new_xyz, idx, p, inx);
    float y0[32];
    linear<6, 32>(w0, b0_, inx, y0);
    accum_stats<32>(y0, stats0);
}

__global__ __launch_bounds__(256) void l1_stats_kernel(
    const float* __restrict__ xyz, const float* __restrict__ points,
    const float* __restrict__ new_xyz, const int* __restrict__ idx,
    const float* __restrict__ w0, const float* __restrict__ b0_,
    const float* __restrict__ g0, const float* __restrict__ be0,
    const float* __restrict__ w1, const float* __restrict__ b1_,
    const float* __restrict__ stats0, float* __restrict__ stats1) {
    __shared__ float sc0[32], sh0[32];
    bn_coef<32>(stats0, g0, be0, sc0, sh0);
    int p = blockIdx.x * 256 + threadIdx.x;
    float inx[6];
    load_in6(xyz, points, new_xyz, idx, p, inx);
    float y0[32];
    linear<6, 32>(w0, b0_, inx, y0);
#pragma unroll
    for (int c = 0; c < 32; c++) y0[c] = fmaxf(fmaf(y0[c], sc0[c], sh0[c]), 0.f);
    float y1[32];
    linear<32, 32>(w1, b1_, y0, y1);
    accum_stats<32>(y1, stats1);
}

__global__ __launch_bounds__(256) void l2_stats_kernel(
    const float* __restrict__ xyz, const float* __restrict__ points,
    const float* __restrict__ new_xyz, const int* __restrict__ idx,
    const float* __restrict__ w0, const float* __restrict__ b0_,
    const float* __restrict__ g0, const float* __restrict__ be0,
    const float* __restrict__ w1, const float* __restrict__ b1_,
    const float* __restrict__ g1, const float* __restrict__ be1,
    const float* __restrict__ w2, const float* __restrict__ b2_,
    const float* __restrict__ stats0, const float* __restrict__ stats1,
    float* __restrict__ stats2) {
    __shared__ float sc0[32], sh0[32], sc1[32], sh1[32];
    bn_coef<32>(stats0, g0, be0, sc0, sh0);
    bn_coef<32>(stats1, g1, be1, sc1, sh1);
    int p = blockIdx.x * 256 + threadIdx.x;
    float inx[6];
    load_in6(xyz, points, new_xyz, idx, p, inx);
    float y0[32];
    linear<6, 32>(w0, b0_, inx, y0);
#pragma unroll
    for (int c = 0; c < 32; c++) y0[c] = fmaxf(fmaf(y0[c], sc0[c], sh0[c]), 0.f);
    float y1[32];
    linear<32, 32>(w1, b1_, y0, y1);
#pragma unroll
    for (int c = 0; c < 32; c++) y1[c] = fmaxf(fmaf(y1[c], sc1[c], sh1[c]), 0.f);
    float y2[64];
    linear<32, 64>(w2, b2_, y1, y2);
    accum_stats<64>(y2, stats2);
}

__global__ __launch_bounds__(256) void final_kernel(
    const float* __restrict__ xyz, const float* __restrict__ points,
    const float* __restrict__ new_xyz, const int* __restrict__ idx,
    const float* __restrict__ w0, const float* __restrict__ b0_,
    const float* __restrict__ g0, const float* __restrict__ be0,
    const float* __restrict__ w1, const float* __restrict__ b1_,
    const float* __restrict__ g1, const float* __restrict__ be1,
    const float* __restrict__ w2, const float* __restrict__ b2_,
    const float* __restrict__ g2, const float* __restrict__ be2,
    const float* __restrict__ stats0, const float* __restrict__ stats1,
    const float* __restrict__ stats2, float* __restrict__ out_points) {
    __shared__ float sc0[32], sh0[32], sc1[32], sh1[32], sc2[64], sh2[64];
    bn_coef<32>(stats0, g0, be0, sc0, sh0);
    bn_coef<32>(stats1, g1, be1, sc1, sh1);
    bn_coef<64>(stats2, g2, be2, sc2, sh2);
    int p = blockIdx.x * 256 + threadIdx.x;
    float inx[6];
    load_in6(xyz, points, new_xyz, idx, p, inx);
    float y0[32];
    linear<6, 32>(w0, b0_, inx, y0);
#pragma unroll
    for (int c = 0; c < 32; c++) y0[c] = fmaxf(fmaf(y0[c], sc0[c], sh0[c]), 0.f);
    float y1[32];
    linear<32, 32>(w1, b1_, y0, y1);
#pragma unroll
    for (int c = 0; c < 32; c++) y1[c] = fmaxf(fmaf(y1[c], sc1[c], sh1[c]), 0.f);
    float y2[64];
    linear<32, 64>(w2, b2_, y1, y2);
    // BN + relu + max over k (k == lane&31; butterfly within each 32-lane half)
#pragma unroll
    for (int c = 0; c < 64; c++) {
        float v = fmaxf(fmaf(y2[c], sc2[c], sh2[c]), 0.f);
#pragma unroll
        for (int off = 1; off < 32; off <<= 1)
            v = fmaxf(v, __shfl_xor(v, off));
        y2[c] = v;
    }
    int lane = threadIdx.x & 63;
    if ((lane & 31) == 0) {                     // k == 0 lanes write their (b,s) row
        int bs = p >> 5;
        float4* o = (float4*)(out_points + (long)bs * 64);
#pragma unroll
        for (int c4 = 0; c4 < 16; c4++)
            o[c4] = make_float4(y2[c4 * 4], y2[c4 * 4 + 1], y2[c4 * 4 + 2], y2[c4 * 4 + 3]);
    }
}

// ---------------------------------------------------------------------------
extern "C" void kernel_launch(void* const* d_in, const int* in_sizes, int n_in,
                              void* d_out, int out_size, void* d_ws, size_t ws_size,
                              hipStream_t stream) {
    (void)in_sizes; (void)n_in; (void)out_size; (void)ws_size;
    const float* xyz    = (const float*)d_in[0];
    const float* points = (const float*)d_in[1];
    const float* w0  = (const float*)d_in[2];
    const float* b0_ = (const float*)d_in[3];
    const float* g0  = (const float*)d_in[4];
    const float* be0 = (const float*)d_in[5];
    const float* w1  = (const float*)d_in[6];
    const float* b1_ = (const float*)d_in[7];
    const float* g1  = (const float*)d_in[8];
    const float* be1 = (const float*)d_in[9];
    const float* w2  = (const float*)d_in[10];
    const float* b2_ = (const float*)d_in[11];
    const float* g2  = (const float*)d_in[12];
    const float* be2 = (const float*)d_in[13];

    float* out        = (float*)d_out;
    float* out_newxyz = out;                 // (8,2048,3)
    float* out_points = out + BB * SS * 3;   // (8,2048,64)

    int*   idx    = (int*)d_ws;              // NP ints = 2MB
    float* stats  = (float*)d_ws + NP;
    float* stats0 = stats;                   // 64 floats (sum32+sq32)
    float* stats1 = stats + 64;              // 64 floats
    float* stats2 = stats + 128;             // 128 floats (sum64+sq64)

    hipMemsetAsync(stats, 0, 256 * sizeof(float), stream);

    fps_kernel<<<BB, 256, 0, stream>>>(xyz, out_newxyz);
    ballq_kernel<<<BB * SS / 4, 256, 0, stream>>>(xyz, out_newxyz, idx);
    l0_stats_kernel<<<NP / 256, 256, 0, stream>>>(xyz, points, out_newxyz, idx, w0, b0_, stats0);
    l1_stats_kernel<<<NP / 256, 256, 0, stream>>>(xyz, points, out_newxyz, idx,
                                                  w0, b0_, g0, be0, w1, b1_, stats0, stats1);
    l2_stats_kernel<<<NP / 256, 256, 0, stream>>>(xyz, points, out_newxyz, idx,
                                                  w0, b0_, g0, be0, w1, b1_, g1, be1,
                                                  w2, b2_, stats0, stats1, stats2);
    final_kernel<<<NP / 256, 256, 0, stream>>>(xyz, points, out_newxyz, idx,
                                               w0, b0_, g0, be0, w1, b1_, g1, be1,
                                               w2, b2_, g2, be2, stats0, stats1, stats2,
                                               out_points);
}

// Round 10
// 3566.653 us; speedup vs baseline: 1.4286x; 1.4286x over previous
//
#include <hip/hip_runtime.h>
#include <math.h>

#define BB 8
#define NN 8192
#define SS 2048
#define KK 32
#define NP (BB*SS*KK)   /* 524288 points through the MLP */
#define EPSF 1e-5f

// ---------------------------------------------------------------------------
// DPP-based wave64 max of a u64 key. Pure VALU. Valid in lane 63.
// ---------------------------------------------------------------------------
template <int CTRL>
__device__ __forceinline__ unsigned long long dpp_max_step(unsigned long long key) {
    unsigned lo = (unsigned)key, hi = (unsigned)(key >> 32);
    unsigned nlo = (unsigned)__builtin_amdgcn_update_dpp((int)lo, (int)lo, CTRL, 0xf, 0xf, false);
    unsigned nhi = (unsigned)__builtin_amdgcn_update_dpp((int)hi, (int)hi, CTRL, 0xf, 0xf, false);
    unsigned long long nk = ((unsigned long long)nhi << 32) | nlo;
    return nk > key ? nk : key;
}

__device__ __forceinline__ unsigned long long wave_max_u64(unsigned long long key) {
    key = dpp_max_step<0x111>(key);  // row_shr:1
    key = dpp_max_step<0x112>(key);  // row_shr:2
    key = dpp_max_step<0x114>(key);  // row_shr:4
    key = dpp_max_step<0x118>(key);  // row_shr:8
    key = dpp_max_step<0x142>(key);  // row_bcast:15
    key = dpp_max_step<0x143>(key);  // row_bcast:31
    return key;
}

// ---------------------------------------------------------------------------
// Bucket-FPS v2 (R8 was correct but serialized dirty tiles in one wave).
// One block (256 thr) per batch. Prologue counting-sorts into 8x8x8 cells;
// 128 tiles of 64 sorted points with tight float4-packed bboxes.
// Per iteration:
//   P1 (tid<128): tile dirty iff d_min(c,bbox) < tile_max (RN-monotone lower
//       bound -> skipping is bit-exact); dirty tiles pushed to a compacted
//       LDS worklist (atomicAdd, ~10-20/iter).
//   [barrier]
//   P2: 4 waves consume worklist strided (wid, wid+4, ...) -> balanced;
//       per tile: dist update + DPP wave-max key -> tkey[tile] (always exact:
//       clean tiles' dists unchanged, dirty refreshed).
//   [barrier]
//   P3: every wave reduces all 128 tkeys (b128 loads + DPP + shfl) -> argmax;
//       tie-break by ORIGINAL index via key = dist<<32 | (8191-orig)<<13 | pos.
// min exactly associative, d uses the reference __f*_rn chain, coords exact
// copies -> bit-identical FPS sequence (validated by R8's pass).
// ---------------------------------------------------------------------------
__global__ __launch_bounds__(256) void fps_kernel(const float* __restrict__ xyz,
                                                  float* __restrict__ out_newxyz) {
#pragma clang fp contract(off)
    int b = blockIdx.x;
    int t = threadIdx.x;
    int wid  = t >> 6;               // 0..3
    int lane = t & 63;
    const float* x = xyz + b * NN * 3;
    float* nout = out_newxyz + b * SS * 3;

    __shared__ float sx[NN], sy[NN], sz[NN];          // 96 KB sorted coords
    __shared__ unsigned short sidx[NN];               // 16 KB orig index
    __shared__ float sdist[NN];                       // 32 KB min-dist
    __shared__ float4 tboxA[128];                     // (mnx,mxx,mny,mxy)
    __shared__ float4 tboxB[128];                     // (mnz,mxz,-,-)
    __shared__ __align__(16) unsigned long long tkey[128];
    __shared__ int wl[128];                           // dirty-tile worklist
    __shared__ int cnt2[2];                           // parity counters
    __shared__ int cellstart[512];
    __shared__ float red[4][6];
    __shared__ int spos0;

    // ---- prologue: batch bbox ----
    float mnx = 1e30f, mxx = -1e30f, mny = 1e30f, mxy = -1e30f, mnz = 1e30f, mxz = -1e30f;
    for (int i = 0; i < NN / 256; i++) {
        int p = t + i * 256;
        float px = x[p * 3 + 0], py = x[p * 3 + 1], pz = x[p * 3 + 2];
        mnx = fminf(mnx, px); mxx = fmaxf(mxx, px);
        mny = fminf(mny, py); mxy = fmaxf(mxy, py);
        mnz = fminf(mnz, pz); mxz = fmaxf(mxz, pz);
    }
#pragma unroll
    for (int off = 1; off < 64; off <<= 1) {
        mnx = fminf(mnx, __shfl_xor(mnx, off)); mxx = fmaxf(mxx, __shfl_xor(mxx, off));
        mny = fminf(mny, __shfl_xor(mny, off)); mxy = fmaxf(mxy, __shfl_xor(mxy, off));
        mnz = fminf(mnz, __shfl_xor(mnz, off)); mxz = fmaxf(mxz, __shfl_xor(mxz, off));
    }
    if (lane == 0) {
        red[wid][0] = mnx; red[wid][1] = mxx; red[wid][2] = mny;
        red[wid][3] = mxy; red[wid][4] = mnz; red[wid][5] = mxz;
    }
    __syncthreads();
    mnx = fminf(fminf(red[0][0], red[1][0]), fminf(red[2][0], red[3][0]));
    mxx = fmaxf(fmaxf(red[0][1], red[1][1]), fmaxf(red[2][1], red[3][1]));
    mny = fminf(fminf(red[0][2], red[1][2]), fminf(red[2][2], red[3][2]));
    mxy = fmaxf(fmaxf(red[0][3], red[1][3]), fmaxf(red[2][3], red[3][3]));
    mnz = fminf(fminf(red[0][4], red[1][4]), fminf(red[2][4], red[3][4]));
    mxz = fmaxf(fmaxf(red[0][5], red[1][5]), fmaxf(red[2][5], red[3][5]));
    float sclx = 8.0f / (mxx - mnx), scly = 8.0f / (mxy - mny), sclz = 8.0f / (mxz - mnz);

    // ---- histogram ----
    cellstart[t] = 0; cellstart[t + 256] = 0;
    __syncthreads();
    for (int i = 0; i < NN / 256; i++) {
        int p = t + i * 256;
        float px = x[p * 3 + 0], py = x[p * 3 + 1], pz = x[p * 3 + 2];
        int ix = min(7, max(0, (int)((px - mnx) * sclx)));
        int iy = min(7, max(0, (int)((py - mny) * scly)));
        int iz = min(7, max(0, (int)((pz - mnz) * sclz)));
        atomicAdd(&cellstart[(iz * 8 + iy) * 8 + ix], 1);
    }
    __syncthreads();
    if (t == 0) {
        int run = 0;
        for (int c2 = 0; c2 < 512; c2++) { int v = cellstart[c2]; cellstart[c2] = run; run += v; }
    }
    __syncthreads();
    // ---- scatter (sort) + dist init ----
    for (int i = 0; i < NN / 256; i++) {
        int p = t + i * 256;
        float px = x[p * 3 + 0], py = x[p * 3 + 1], pz = x[p * 3 + 2];
        int ix = min(7, max(0, (int)((px - mnx) * sclx)));
        int iy = min(7, max(0, (int)((py - mny) * scly)));
        int iz = min(7, max(0, (int)((pz - mnz) * sclz)));
        int pos = atomicAdd(&cellstart[(iz * 8 + iy) * 8 + ix], 1);
        sx[pos] = px; sy[pos] = py; sz[pos] = pz;
        sidx[pos] = (unsigned short)p;
        if (p == 0) spos0 = pos;
        sdist[p] = 1e10f;
    }
    if (t < 128) tkey[t] = ((unsigned long long)__float_as_uint(1e10f)) << 32;
    if (t == 0) { cnt2[0] = 0; cnt2[1] = 0; }
    __syncthreads();
    // ---- tile bboxes (tight) ----
    for (int tt = 0; tt < 32; tt++) {
        int tile = wid * 32 + tt;
        int q = tile * 64 + lane;
        float vx = sx[q], vy = sy[q], vz = sz[q];
        float ax = vx, bx2 = vx, ay = vy, by2 = vy, az = vz, bz2 = vz;
#pragma unroll
        for (int off = 1; off < 64; off <<= 1) {
            ax = fminf(ax, __shfl_xor(ax, off)); bx2 = fmaxf(bx2, __shfl_xor(bx2, off));
            ay = fminf(ay, __shfl_xor(ay, off)); by2 = fmaxf(by2, __shfl_xor(by2, off));
            az = fminf(az, __shfl_xor(az, off)); bz2 = fmaxf(bz2, __shfl_xor(bz2, off));
        }
        if (lane == 0) {
            tboxA[tile] = make_float4(ax, bx2, ay, by2);
            tboxB[tile] = make_float4(az, bz2, 0.f, 0.f);
        }
    }
    __syncthreads();

    int sc = spos0;
    float cx = sx[sc], cy = sy[sc], cz = sz[sc];

    for (int it = 0; it < SS; it++) {
        if (t == 0) {
            nout[it * 3 + 0] = cx;
            nout[it * 3 + 1] = cy;
            nout[it * 3 + 2] = cz;
        }
        // P1: bbox lower-bound test; push dirty tiles to worklist
        if (t < 128) {
            float4 A = tboxA[t];
            float4 Bb = tboxB[t];
            float t1 = __fsub_rn(A.x, cx);
            float t2 = __fsub_rn(cx, A.y);
            float tx = fmaxf(fmaxf(t1, t2), 0.f);
            t1 = __fsub_rn(A.z, cy);
            t2 = __fsub_rn(cy, A.w);
            float ty = fmaxf(fmaxf(t1, t2), 0.f);
            t1 = __fsub_rn(Bb.x, cz);
            t2 = __fsub_rn(cz, Bb.y);
            float tz = fmaxf(fmaxf(t1, t2), 0.f);
            float dmin = __fadd_rn(__fadd_rn(__fmul_rn(tx, tx), __fmul_rn(ty, ty)),
                                   __fmul_rn(tz, tz));
            float tmax = __uint_as_float((unsigned)(tkey[t] >> 32));
            if (dmin < tmax) {
                int pos = atomicAdd(&cnt2[it & 1], 1);
                wl[pos] = t;
            }
        }
        __syncthreads();                               // worklist ready
        int cnt = cnt2[it & 1];
        if (t == 0) cnt2[(it + 1) & 1] = 0;            // reset other parity
        // P2: balanced dirty-tile updates (waves stride the worklist)
        for (int wi = wid; wi < cnt; wi += 4) {
            int tile = wl[wi];
            int q = tile * 64 + lane;
            float dx = __fsub_rn(sx[q], cx);
            float dy = __fsub_rn(sy[q], cy);
            float dz = __fsub_rn(sz[q], cz);
            float d  = __fadd_rn(__fadd_rn(__fmul_rn(dx, dx), __fmul_rn(dy, dy)),
                                 __fmul_rn(dz, dz));
            float e = fminf(sdist[q], d);
            sdist[q] = e;
            unsigned orig = sidx[q];
            unsigned long long key = ((unsigned long long)__float_as_uint(e) << 32)
                                   | ((8191u - orig) << 13) | (unsigned)q;
            key = wave_max_u64(key);
            if (lane == 63) tkey[tile] = key;
        }
        __syncthreads();                               // tkey fresh
        // P3: every wave reduces all 128 tile keys
        ulonglong2 kp = *(const ulonglong2*)&tkey[lane * 2];
        unsigned long long k = kp.x > kp.y ? kp.x : kp.y;
        k = wave_max_u64(k);
        k = __shfl(k, 63);
        int gs = (int)((unsigned)k & 0x1FFFu);
        cx = sx[gs]; cy = sy[gs]; cz = sz[gs];
    }
}

// ---------------------------------------------------------------------------
// Ball query: one wave per query. Ordered compaction of first 32 in-radius
// indices (== reference's where->sort->truncate), pad with first index.
// ---------------------------------------------------------------------------
__global__ __launch_bounds__(256) void ballq_kernel(const float* __restrict__ xyz,
                                                    const float* __restrict__ new_xyz,
                                                    int* __restrict__ idx_out) {
    int q    = blockIdx.x * 4 + (threadIdx.x >> 6);
    int lane = threadIdx.x & 63;
    int b    = q >> 11;                        // q / SS
    const float* x = xyz + b * NN * 3;
    const float* c = new_xyz + q * 3;
    float cx = c[0], cy = c[1], cz = c[2];
    int* out = idx_out + q * KK;
    const float R2 = (float)(0.2 * 0.2);       // match reference double->f32 cast

    int count = 0;
    int first = -1;
    for (int base = 0; base < NN; base += 64) {
        int p = base + lane;
        float dx = __fsub_rn(x[p * 3 + 0], cx);
        float dy = __fsub_rn(x[p * 3 + 1], cy);
        float dz = __fsub_rn(x[p * 3 + 2], cz);
        float d  = __fadd_rn(__fadd_rn(__fmul_rn(dx, dx), __fmul_rn(dy, dy)),
                             __fmul_rn(dz, dz));
        bool in = !(d > R2);
        unsigned long long m = __ballot(in);
        if (first < 0 && m != 0ull) first = base + __ffsll((unsigned long long)m) - 1;
        int pre = __popcll(m & ((1ull << lane) - 1ull));
        int pos = count + pre;
        if (in && pos < KK) out[pos] = p;
        count += __popcll(m);
        if (count >= KK) break;                 // wave-uniform
    }
    for (int i2 = count + lane; i2 < KK; i2 += 64) out[i2] = first;
}

// ---------------------------------------------------------------------------
// MLP helpers (thread-per-point recompute chain; weights via uniform s_loads)
// ---------------------------------------------------------------------------
__device__ __forceinline__ void load_in6(const float* __restrict__ xyz,
                                         const float* __restrict__ points,
                                         const float* __restrict__ new_xyz,
                                         const int* __restrict__ idx, int p, float inx[6]) {
    int bs = p >> 5;
    int b  = bs >> 11;
    int pt = idx[p];
    const float* xb = xyz + ((long)b * NN + pt) * 3;
    const float* pb = points + ((long)b * NN + pt) * 3;
    const float* nx = new_xyz + bs * 3;
    inx[0] = xb[0] - nx[0];
    inx[1] = xb[1] - nx[1];
    inx[2] = xb[2] - nx[2];
    inx[3] = pb[0];
    inx[4] = pb[1];
    inx[5] = pb[2];
}

template <int CIN, int COUT>
__device__ __forceinline__ void linear(const float* __restrict__ w,
                                       const float* __restrict__ bias,
                                       const float* xin, float* yout) {
#pragma unroll
    for (int o = 0; o < COUT; o++) {
        float acc = bias[o];
#pragma unroll
        for (int j = 0; j < CIN; j++) acc = fmaf(w[o * CIN + j], xin[j], acc);
        yout[o] = acc;
    }
}

// compute per-channel BN scale/shift from raw sums (threads 0..C-1)
template <int C>
__device__ __forceinline__ void bn_coef(const float* __restrict__ stats,
                                        const float* __restrict__ g,
                                        const float* __restrict__ be,
                                        float* s_sc, float* s_sh) {
    int t = threadIdx.x;
    if (t < C) {
        float mean = stats[t] * (1.0f / (float)NP);
        float var  = stats[C + t] * (1.0f / (float)NP) - mean * mean;
        float rstd = 1.0f / sqrtf(var + EPSF);
        float sc = g[t] * rstd;
        s_sc[t] = sc;
        s_sh[t] = be[t] - mean * sc;
    }
    __syncthreads();
}

// block-level channel sums via LDS transpose (33.8KB), one atomic/chan/block
template <int C>
__device__ __forceinline__ void accum_stats(const float* y, float* __restrict__ gstats) {
    __shared__ float buf[256][33];
    int t = threadIdx.x;
#pragma unroll
    for (int h = 0; h < C / 32; h++) {
        __syncthreads();
#pragma unroll
        for (int c = 0; c < 32; c++) buf[t][c] = y[h * 32 + c];
        __syncthreads();
        if (t < 32) {
            float s = 0.f, sq = 0.f;
            for (int r = 0; r < 256; r++) {
                float v = buf[r][t];
                s += v;
                sq = fmaf(v, v, sq);
            }
            atomicAdd(&gstats[h * 32 + t], s);
            atomicAdd(&gstats[C + h * 32 + t], sq);
        }
    }
}

__global__ __launch_bounds__(256) void l0_stats_kernel(
    const float* __restrict__ xyz, const float* __restrict__ points,
    const float* __restrict__ new_xyz, const int* __restrict__ idx,
    const float* __restrict__ w0, const float* __restrict__ b0_,
    float* __restrict__ stats0) {
    int p = blockIdx.x * 256 + threadIdx.x;
    float inx[6];
    load_in6(xyz, points, new_xyz, idx, p, inx);
    float y0[32];
    linear<6, 32>(w0, b0_, inx, y0);
    accum_stats<32>(y0, stats0);
}

__global__ __launch_bounds__(256) void l1_stats_kernel(
    const float* __restrict__ xyz, const float* __restrict__ points,
    const float* __restrict__ new_xyz, const int* __restrict__ idx,
    const float* __restrict__ w0, const float* __restrict__ b0_,
    const float* __restrict__ g0, const float* __restrict__ be0,
    const float* __restrict__ w1, const float* __restrict__ b1_,
    const float* __restrict__ stats0, float* __restrict__ stats1) {
    __shared__ float sc0[32], sh0[32];
    bn_coef<32>(stats0, g0, be0, sc0, sh0);
    int p = blockIdx.x * 256 + threadIdx.x;
    float inx[6];
    load_in6(xyz, points, new_xyz, idx, p, inx);
    float y0[32];
    linear<6, 32>(w0, b0_, inx, y0);
#pragma unroll
    for (int c = 0; c < 32; c++) y0[c] = fmaxf(fmaf(y0[c], sc0[c], sh0[c]), 0.f);
    float y1[32];
    linear<32, 32>(w1, b1_, y0, y1);
    accum_stats<32>(y1, stats1);
}

__global__ __launch_bounds__(256) void l2_stats_kernel(
    const float* __restrict__ xyz, const float* __restrict__ points,
    const float* __restrict__ new_xyz, const int* __restrict__ idx,
    const float* __restrict__ w0, const float* __restrict__ b0_,
    const float* __restrict__ g0, const float* __restrict__ be0,
    const float* __restrict__ w1, const float* __restrict__ b1_,
    const float* __restrict__ g1, const float* __restrict__ be1,
    const float* __restrict__ w2, const float* __restrict__ b2_,
    const float* __restrict__ stats0, const float* __restrict__ stats1,
    float* __restrict__ stats2) {
    __shared__ float sc0[32], sh0[32], sc1[32], sh1[32];
    bn_coef<32>(stats0, g0, be0, sc0, sh0);
    bn_coef<32>(stats1, g1, be1, sc1, sh1);
    int p = blockIdx.x * 256 + threadIdx.x;
    float inx[6];
    load_in6(xyz, points, new_xyz, idx, p, inx);
    float y0[32];
    linear<6, 32>(w0, b0_, inx, y0);
#pragma unroll
    for (int c = 0; c < 32; c++) y0[c] = fmaxf(fmaf(y0[c], sc0[c], sh0[c]), 0.f);
    float y1[32];
    linear<32, 32>(w1, b1_, y0, y1);
#pragma unroll
    for (int c = 0; c < 32; c++) y1[c] = fmaxf(fmaf(y1[c], sc1[c], sh1[c]), 0.f);
    float y2[64];
    linear<32, 64>(w2, b2_, y1, y2);
    accum_stats<64>(y2, stats2);
}

__global__ __launch_bounds__(256) void final_kernel(
    const float* __restrict__ xyz, const float* __restrict__ points,
    const float* __restrict__ new_xyz, const int* __restrict__ idx,
    const float* __restrict__ w0, const float* __restrict__ b0_,
    const float* __restrict__ g0, const float* __restrict__ be0,
    const float* __restrict__ w1, const float* __restrict__ b1_,
    const float* __restrict__ g1, const float* __restrict__ be1,
    const float* __restrict__ w2, const float* __restrict__ b2_,
    const float* __restrict__ g2, const float* __restrict__ be2,
    const float* __restrict__ stats0, const float* __restrict__ stats1,
    const float* __restrict__ stats2, float* __restrict__ out_points) {
    __shared__ float sc0[32], sh0[32], sc1[32], sh1[32], sc2[64], sh2[64];
    bn_coef<32>(stats0, g0, be0, sc0, sh0);
    bn_coef<32>(stats1, g1, be1, sc1, sh1);
    bn_coef<64>(stats2, g2, be2, sc2, sh2);
    int p = blockIdx.x * 256 + threadIdx.x;
    float inx[6];
    load_in6(xyz, points, new_xyz, idx, p, inx);
    float y0[32];
    linear<6, 32>(w0, b0_, inx, y0);
#pragma unroll
    for (int c = 0; c < 32; c++) y0[c] = fmaxf(fmaf(y0[c], sc0[c], sh0[c]), 0.f);
    float y1[32];
    linear<32, 32>(w1, b1_, y0, y1);
#pragma unroll
    for (int c = 0; c < 32; c++) y1[c] = fmaxf(fmaf(y1[c], sc1[c], sh1[c]), 0.f);
    float y2[64];
    linear<32, 64>(w2, b2_, y1, y2);
    // BN + relu + max over k (k == lane&31; butterfly within each 32-lane half)
#pragma unroll
    for (int c = 0; c < 64; c++) {
        float v = fmaxf(fmaf(y2[c], sc2[c], sh2[c]), 0.f);
#pragma unroll
        for (int off = 1; off < 32; off <<= 1)
            v = fmaxf(v, __shfl_xor(v, off));
        y2[c] = v;
    }
    int lane = threadIdx.x & 63;
    if ((lane & 31) == 0) {                     // k == 0 lanes write their (b,s) row
        int bs = p >> 5;
        float4* o = (float4*)(out_points + (long)bs * 64);
#pragma unroll
        for (int c4 = 0; c4 < 16; c4++)
            o[c4] = make_float4(y2[c4 * 4], y2[c4 * 4 + 1], y2[c4 * 4 + 2], y2[c4 * 4 + 3]);
    }
}

// ---------------------------------------------------------------------------
extern "C" void kernel_launch(void* const* d_in, const int* in_sizes, int n_in,
                              void* d_out, int out_size, void* d_ws, size_t ws_size,
                              hipStream_t stream) {
    (void)in_sizes; (void)n_in; (void)out_size; (void)ws_size;
    const float* xyz    = (const float*)d_in[0];
    const float* points = (const float*)d_in[1];
    const float* w0  = (const float*)d_in[2];
    const float* b0_ = (const float*)d_in[3];
    const float* g0  = (const float*)d_in[4];
    const float* be0 = (const float*)d_in[5];
    const float* w1  = (const float*)d_in[6];
    const float* b1_ = (const float*)d_in[7];
    const float* g1  = (const float*)d_in[8];
    const float* be1 = (const float*)d_in[9];
    const float* w2  = (const float*)d_in[10];
    const float* b2_ = (const float*)d_in[11];
    const float* g2  = (const float*)d_in[12];
    const float* be2 = (const float*)d_in[13];

    float* out        = (float*)d_out;
    float* out_newxyz = out;                 // (8,2048,3)
    float* out_points = out + BB * SS * 3;   // (8,2048,64)

    int*   idx    = (int*)d_ws;              // NP ints = 2MB
    float* stats  = (float*)d_ws + NP;
    float* stats0 = stats;                   // 64 floats (sum32+sq32)
    float* stats1 = stats + 64;              // 64 floats
    float* stats2 = stats + 128;             // 128 floats (sum64+sq64)

    hipMemsetAsync(stats, 0, 256 * sizeof(float), stream);

    fps_kernel<<<BB, 256, 0, stream>>>(xyz, out_newxyz);
    ballq_kernel<<<BB * SS / 4, 256, 0, stream>>>(xyz, out_newxyz, idx);
    l0_stats_kernel<<<NP / 256, 256, 0, stream>>>(xyz, points, out_newxyz, idx, w0, b0_, stats0);
    l1_stats_kernel<<<NP / 256, 256, 0, stream>>>(xyz, points, out_newxyz, idx,
                                                  w0, b0_, g0, be0, w1, b1_, stats0, stats1);
    l2_stats_kernel<<<NP / 256, 256, 0, stream>>>(xyz, points, out_newxyz, idx,
                                                  w0, b0_, g0, be0, w1, b1_, g1, be1,
                                                  w2, b2_, stats0, stats1, stats2);
    final_kernel<<<NP / 256, 256, 0, stream>>>(xyz, points, out_newxyz, idx,
                                               w0, b0_, g0, be0, w1, b1_, g1, be1,
                                               w2, b2_, g2, be2, stats0, stats1, stats2,
                                               out_points);
}

// Round 11
// 2404.591 us; speedup vs baseline: 2.1190x; 1.4833x over previous
//
#include <hip/hip_runtime.h>
#include <math.h>

#define BB 8
#define NN 8192
#define SS 2048
#define KK 32
#define NP (BB*SS*KK)   /* 524288 points through the MLP */
#define EPSF 1e-5f
#define TT 256          /* fps threads per block (R6: W=1 wave/SIMD optimal) */

// ---------------------------------------------------------------------------
// DPP-based wave64 max of a u64 key (dist_bits<<32 | ~p). Pure VALU.
// ---------------------------------------------------------------------------
template <int CTRL>
__device__ __forceinline__ unsigned long long dpp_max_step(unsigned long long key) {
    unsigned lo = (unsigned)key, hi = (unsigned)(key >> 32);
    unsigned nlo = (unsigned)__builtin_amdgcn_update_dpp((int)lo, (int)lo, CTRL, 0xf, 0xf, false);
    unsigned nhi = (unsigned)__builtin_amdgcn_update_dpp((int)hi, (int)hi, CTRL, 0xf, 0xf, false);
    unsigned long long nk = ((unsigned long long)nhi << 32) | nlo;
    return nk > key ? nk : key;
}

__device__ __forceinline__ unsigned long long wave_max_u64(unsigned long long key) {
    key = dpp_max_step<0x111>(key);  // row_shr:1
    key = dpp_max_step<0x112>(key);  // row_shr:2
    key = dpp_max_step<0x114>(key);  // row_shr:4
    key = dpp_max_step<0x118>(key);  // row_shr:8
    key = dpp_max_step<0x142>(key);  // row_bcast:15
    key = dpp_max_step<0x143>(key);  // row_bcast:31
    return key;                      // valid in lane 63
}

// ---------------------------------------------------------------------------
// FPS (eager, R6 structure, scalar registers): one block per batch (R4:
// cross-WG exchange ~2.5us/iter -> single-CU per batch is structural).
// 256 threads = 1 wave/SIMD (R5/R6: per-iter time flat-to-worse with more
// waves). 32 points/thread in PLAIN float arrays — R7 proved v2f source
// never becomes v_pk_* ops, so vector types only add insert/extract movs
// (~200 insts/iter). Update = 10 VALU/pt; 4 split max accumulators shorten
// the fmaxf dep chain; deferred argmax resolve scans high->low (smallest
// slot among ties == np.argmax). u64 key (dist<<32 | ~p) -> DPP wave max ->
// parity LDS slots -> 4-key scan -> centroid from 128KB LDS float4 copy.
// Bit-exact: contract(off), ((dx*dx+dy*dy)+dz*dz) via __f*_rn, exact coord
// copies. Tail: fps block 0 zeroes the BN stats buffer (replaces memset).
// ---------------------------------------------------------------------------
__global__ __launch_bounds__(TT) void fps_kernel(const float* __restrict__ xyz,
                                                 float* __restrict__ out_newxyz,
                                                 float* __restrict__ stats) {
#pragma clang fp contract(off)
    const int PPT = NN / TT;         // 32 points per thread
    int b = blockIdx.x;
    int t = threadIdx.x;
    int wid  = t >> 6;               // 0..3
    int lane = t & 63;
    const float* x = xyz + b * NN * 3;
    float* nout = out_newxyz + b * SS * 3;

    __shared__ float4 lxyz[NN];                             // 128 KB coord copy
    __shared__ __align__(16) unsigned long long skey[2][4]; // parity wave keys

    float px[PPT], py[PPT], pz[PPT], dist[PPT];
#pragma unroll
    for (int j = 0; j < PPT; j++) {
        int p = t + j * TT;
        float vx = x[p * 3 + 0];
        float vy = x[p * 3 + 1];
        float vz = x[p * 3 + 2];
        px[j] = vx; py[j] = vy; pz[j] = vz;
        lxyz[p] = make_float4(vx, vy, vz, 0.f);
        dist[j] = 1e10f;
    }
    __syncthreads();
    float4 c0 = lxyz[0];                              // far = 0 initially
    float cx = c0.x, cy = c0.y, cz = c0.z;

    for (int it = 0; it < SS; it++) {
        if (t == 0) {                                  // record current far point
            nout[it * 3 + 0] = cx;
            nout[it * 3 + 1] = cy;
            nout[it * 3 + 2] = cz;
        }
        // scalar update, 10 VALU/pt; 4 split max accumulators (dep chain /4)
        float m0 = -1.0f, m1 = -1.0f, m2 = -1.0f, m3 = -1.0f;
#pragma unroll
        for (int j = 0; j < PPT; j++) {
            float dx = __fsub_rn(px[j], cx);
            float dy = __fsub_rn(py[j], cy);
            float dz = __fsub_rn(pz[j], cz);
            float d  = __fadd_rn(__fadd_rn(__fmul_rn(dx, dx), __fmul_rn(dy, dy)),
                                 __fmul_rn(dz, dz));
            float e = fminf(dist[j], d);
            dist[j] = e;
            if ((j & 3) == 0)      m0 = fmaxf(m0, e);
            else if ((j & 3) == 1) m1 = fmaxf(m1, e);
            else if ((j & 3) == 2) m2 = fmaxf(m2, e);
            else                   m3 = fmaxf(m3, e);
        }
        float lmax = fmaxf(fmaxf(m0, m1), fmaxf(m2, m3));
        // resolve smallest slot attaining lmax (scan high->low, low overwrites)
        int li = 0;
#pragma unroll
        for (int j = PPT - 1; j >= 0; j--)
            li = (dist[j] == lmax) ? j : li;
        int p = t + (li << 8);                         // global point index
        unsigned long long key =
            ((unsigned long long)__float_as_uint(lmax) << 32) | (unsigned)(~p);
        key = wave_max_u64(key);                       // DPP, valid in lane 63
        if (lane == 63) skey[it & 1][wid] = key;
        __syncthreads();
        const ulonglong2* sk = (const ulonglong2*)&skey[it & 1][0];
        ulonglong2 ab = sk[0];                         // 2x ds_read_b128
        ulonglong2 cd = sk[1];
        unsigned long long k = ab.x;
        k = (ab.y > k) ? ab.y : k;
        k = (cd.x > k) ? cd.x : k;
        k = (cd.y > k) ? cd.y : k;
        int gi = (int)(~(unsigned)k) & (NN - 1);
        float4 c = lxyz[gi];                           // one broadcast ds_read_b128
        cx = c.x; cy = c.y; cz = c.z;
    }
    if (b == 0) stats[t] = 0.f;                        // zero BN stats (256 floats)
}

// ---------------------------------------------------------------------------
// Ball query: one wave per query. Ordered compaction of first 32 in-radius
// indices (== reference's where->sort->truncate), pad with first index.
// ---------------------------------------------------------------------------
__global__ __launch_bounds__(256) void ballq_kernel(const float* __restrict__ xyz,
                                                    const float* __restrict__ new_xyz,
                                                    int* __restrict__ idx_out) {
    int q    = blockIdx.x * 4 + (threadIdx.x >> 6);
    int lane = threadIdx.x & 63;
    int b    = q >> 11;                        // q / SS
    const float* x = xyz + b * NN * 3;
    const float* c = new_xyz + q * 3;
    float cx = c[0], cy = c[1], cz = c[2];
    int* out = idx_out + q * KK;
    const float R2 = (float)(0.2 * 0.2);       // match reference double->f32 cast

    int count = 0;
    int first = -1;
    for (int base = 0; base < NN; base += 64) {
        int p = base + lane;
        float dx = __fsub_rn(x[p * 3 + 0], cx);
        float dy = __fsub_rn(x[p * 3 + 1], cy);
        float dz = __fsub_rn(x[p * 3 + 2], cz);
        float d  = __fadd_rn(__fadd_rn(__fmul_rn(dx, dx), __fmul_rn(dy, dy)),
                             __fmul_rn(dz, dz));
        bool in = !(d > R2);
        unsigned long long m = __ballot(in);
        if (first < 0 && m != 0ull) first = base + __ffsll((unsigned long long)m) - 1;
        int pre = __popcll(m & ((1ull << lane) - 1ull));
        int pos = count + pre;
        if (in && pos < KK) out[pos] = p;
        count += __popcll(m);
        if (count >= KK) break;                 // wave-uniform
    }
    for (int i2 = count + lane; i2 < KK; i2 += 64) out[i2] = first;
}

// ---------------------------------------------------------------------------
// MLP helpers (thread-per-point recompute chain; weights via uniform s_loads)
// ---------------------------------------------------------------------------
__device__ __forceinline__ void load_in6(const float* __restrict__ xyz,
                                         const float* __restrict__ points,
                                         const float* __restrict__ new_xyz,
                                         const int* __restrict__ idx, int p, float inx[6]) {
    int bs = p >> 5;
    int b  = bs >> 11;
    int pt = idx[p];
    const float* xb = xyz + ((long)b * NN + pt) * 3;
    const float* pb = points + ((long)b * NN + pt) * 3;
    const float* nx = new_xyz + bs * 3;
    inx[0] = xb[0] - nx[0];
    inx[1] = xb[1] - nx[1];
    inx[2] = xb[2] - nx[2];
    inx[3] = pb[0];
    inx[4] = pb[1];
    inx[5] = pb[2];
}

template <int CIN, int COUT>
__device__ __forceinline__ void linear(const float* __restrict__ w,
                                       const float* __restrict__ bias,
                                       const float* xin, float* yout) {
#pragma unroll
    for (int o = 0; o < COUT; o++) {
        float acc = bias[o];
#pragma unroll
        for (int j = 0; j < CIN; j++) acc = fmaf(w[o * CIN + j], xin[j], acc);
        yout[o] = acc;
    }
}

// compute per-channel BN scale/shift from raw sums (threads 0..C-1)
template <int C>
__device__ __forceinline__ void bn_coef(const float* __restrict__ stats,
                                        const float* __restrict__ g,
                                        const float* __restrict__ be,
                                        float* s_sc, float* s_sh) {
    int t = threadIdx.x;
    if (t < C) {
        float mean = stats[t] * (1.0f / (float)NP);
        float var  = stats[C + t] * (1.0f / (float)NP) - mean * mean;
        float rstd = 1.0f / sqrtf(var + EPSF);
        float sc = g[t] * rstd;
        s_sc[t] = sc;
        s_sh[t] = be[t] - mean * sc;
    }
    __syncthreads();
}

// block-level channel sums via LDS transpose (33.8KB), one atomic/chan/block
template <int C>
__device__ __forceinline__ void accum_stats(const float* y, float* __restrict__ gstats) {
    __shared__ float buf[256][33];
    int t = threadIdx.x;
#pragma unroll
    for (int h = 0; h < C / 32; h++) {
        __syncthreads();
#pragma unroll
        for (int c = 0; c < 32; c++) buf[t][c] = y[h * 32 + c];
        __syncthreads();
        if (t < 32) {
            float s = 0.f, sq = 0.f;
            for (int r = 0; r < 256; r++) {
                float v = buf[r][t];
                s += v;
                sq = fmaf(v, v, sq);
            }
            atomicAdd(&gstats[h * 32 + t], s);
            atomicAdd(&gstats[C + h * 32 + t], sq);
        }
    }
}

__global__ __launch_bounds__(256) void l0_stats_kernel(
    const float* __restrict__ xyz, const float* __restrict__ points,
    const float* __restrict__ new_xyz, const int* __restrict__ idx,
    const float* __restrict__ w0, const float* __restrict__ b0_,
    float* __restrict__ stats0) {
    int p = blockIdx.x * 256 + threadIdx.x;
    float inx[6];
    load_in6(xyz, points, new_xyz, idx, p, inx);
    float y0[32];
    linear<6, 32>(w0, b0_, inx, y0);
    accum_stats<32>(y0, stats0);
}

__global__ __launch_bounds__(256) void l1_stats_kernel(
    const float* __restrict__ xyz, const float* __restrict__ points,
    const float* __restrict__ new_xyz, const int* __restrict__ idx,
    const float* __restrict__ w0, const float* __restrict__ b0_,
    const float* __restrict__ g0, const float* __restrict__ be0,
    const float* __restrict__ w1, const float* __restrict__ b1_,
    const float* __restrict__ stats0, float* __restrict__ stats1) {
    __shared__ float sc0[32], sh0[32];
    bn_coef<32>(stats0, g0, be0, sc0, sh0);
    int p = blockIdx.x * 256 + threadIdx.x;
    float inx[6];
    load_in6(xyz, points, new_xyz, idx, p, inx);
    float y0[32];
    linear<6, 32>(w0, b0_, inx, y0);
#pragma unroll
    for (int c = 0; c < 32; c++) y0[c] = fmaxf(fmaf(y0[c], sc0[c], sh0[c]), 0.f);
    float y1[32];
    linear<32, 32>(w1, b1_, y0, y1);
    accum_stats<32>(y1, stats1);
}

__global__ __launch_bounds__(256) void l2_stats_kernel(
    const float* __restrict__ xyz, const float* __restrict__ points,
    const float* __restrict__ new_xyz, const int* __restrict__ idx,
    const float* __restrict__ w0, const float* __restrict__ b0_,
    const float* __restrict__ g0, const float* __restrict__ be0,
    const float* __restrict__ w1, const float* __restrict__ b1_,
    const float* __restrict__ g1, const float* __restrict__ be1,
    const float* __restrict__ w2, const float* __restrict__ b2_,
    const float* __restrict__ stats0, const float* __restrict__ stats1,
    float* __restrict__ stats2) {
    __shared__ float sc0[32], sh0[32], sc1[32], sh1[32];
    bn_coef<32>(stats0, g0, be0, sc0, sh0);
    bn_coef<32>(stats1, g1, be1, sc1, sh1);
    int p = blockIdx.x * 256 + threadIdx.x;
    float inx[6];
    load_in6(xyz, points, new_xyz, idx, p, inx);
    float y0[32];
    linear<6, 32>(w0, b0_, inx, y0);
#pragma unroll
    for (int c = 0; c < 32; c++) y0[c] = fmaxf(fmaf(y0[c], sc0[c], sh0[c]), 0.f);
    float y1[32];
    linear<32, 32>(w1, b1_, y0, y1);
#pragma unroll
    for (int c = 0; c < 32; c++) y1[c] = fmaxf(fmaf(y1[c], sc1[c], sh1[c]), 0.f);
    float y2[64];
    linear<32, 64>(w2, b2_, y1, y2);
    accum_stats<64>(y2, stats2);
}

__global__ __launch_bounds__(256) void final_kernel(
    const float* __restrict__ xyz, const float* __restrict__ points,
    const float* __restrict__ new_xyz, const int* __restrict__ idx,
    const float* __restrict__ w0, const float* __restrict__ b0_,
    const float* __restrict__ g0, const float* __restrict__ be0,
    const float* __restrict__ w1, const float* __restrict__ b1_,
    const float* __restrict__ g1, const float* __restrict__ be1,
    const float* __restrict__ w2, const float* __restrict__ b2_,
    const float* __restrict__ g2, const float* __restrict__ be2,
    const float* __restrict__ stats0, const float* __restrict__ stats1,
    const float* __restrict__ stats2, float* __restrict__ out_points) {
    __shared__ float sc0[32], sh0[32], sc1[32], sh1[32], sc2[64], sh2[64];
    bn_coef<32>(stats0, g0, be0, sc0, sh0);
    bn_coef<32>(stats1, g1, be1, sc1, sh1);
    bn_coef<64>(stats2, g2, be2, sc2, sh2);
    int p = blockIdx.x * 256 + threadIdx.x;
    float inx[6];
    load_in6(xyz, points, new_xyz, idx, p, inx);
    float y0[32];
    linear<6, 32>(w0, b0_, inx, y0);
#pragma unroll
    for (int c = 0; c < 32; c++) y0[c] = fmaxf(fmaf(y0[c], sc0[c], sh0[c]), 0.f);
    float y1[32];
    linear<32, 32>(w1, b1_, y0, y1);
#pragma unroll
    for (int c = 0; c < 32; c++) y1[c] = fmaxf(fmaf(y1[c], sc1[c], sh1[c]), 0.f);
    float y2[64];
    linear<32, 64>(w2, b2_, y1, y2);
    // BN + relu + max over k (k == lane&31; butterfly within each 32-lane half)
#pragma unroll
    for (int c = 0; c < 64; c++) {
        float v = fmaxf(fmaf(y2[c], sc2[c], sh2[c]), 0.f);
#pragma unroll
        for (int off = 1; off < 32; off <<= 1)
            v = fmaxf(v, __shfl_xor(v, off));
        y2[c] = v;
    }
    int lane = threadIdx.x & 63;
    if ((lane & 31) == 0) {                     // k == 0 lanes write their (b,s) row
        int bs = p >> 5;
        float4* o = (float4*)(out_points + (long)bs * 64);
#pragma unroll
        for (int c4 = 0; c4 < 16; c4++)
            o[c4] = make_float4(y2[c4 * 4], y2[c4 * 4 + 1], y2[c4 * 4 + 2], y2[c4 * 4 + 3]);
    }
}

// ---------------------------------------------------------------------------
extern "C" void kernel_launch(void* const* d_in, const int* in_sizes, int n_in,
                              void* d_out, int out_size, void* d_ws, size_t ws_size,
                              hipStream_t stream) {
    (void)in_sizes; (void)n_in; (void)out_size; (void)ws_size;
    const float* xyz    = (const float*)d_in[0];
    const float* points = (const float*)d_in[1];
    const float* w0  = (const float*)d_in[2];
    const float* b0_ = (const float*)d_in[3];
    const float* g0  = (const float*)d_in[4];
    const float* be0 = (const float*)d_in[5];
    const float* w1  = (const float*)d_in[6];
    const float* b1_ = (const float*)d_in[7];
    const float* g1  = (const float*)d_in[8];
    const float* be1 = (const float*)d_in[9];
    const float* w2  = (const float*)d_in[10];
    const float* b2_ = (const float*)d_in[11];
    const float* g2  = (const float*)d_in[12];
    const float* be2 = (const float*)d_in[13];

    float* out        = (float*)d_out;
    float* out_newxyz = out;                 // (8,2048,3)
    float* out_points = out + BB * SS * 3;   // (8,2048,64)

    int*   idx    = (int*)d_ws;              // NP ints = 2MB
    float* stats  = (float*)d_ws + NP;
    float* stats0 = stats;                   // 64 floats (sum32+sq32)
    float* stats1 = stats + 64;              // 64 floats
    float* stats2 = stats + 128;             // 128 floats (sum64+sq64)

    // stats zeroing folded into fps_kernel (block 0 writes 256 zeros at end)
    fps_kernel<<<BB, TT, 0, stream>>>(xyz, out_newxyz, stats);
    ballq_kernel<<<BB * SS / 4, 256, 0, stream>>>(xyz, out_newxyz, idx);
    l0_stats_kernel<<<NP / 256, 256, 0, stream>>>(xyz, points, out_newxyz, idx, w0, b0_, stats0);
    l1_stats_kernel<<<NP / 256, 256, 0, stream>>>(xyz, points, out_newxyz, idx,
                                                  w0, b0_, g0, be0, w1, b1_, stats0, stats1);
    l2_stats_kernel<<<NP / 256, 256, 0, stream>>>(xyz, points, out_newxyz, idx,
                                                  w0, b0_, g0, be0, w1, b1_, g1, be1,
                                                  w2, b2_, stats0, stats1, stats2);
    final_kernel<<<NP / 256, 256, 0, stream>>>(xyz, points, out_newxyz, idx,
                                               w0, b0_, g0, be0, w1, b1_, g1, be1,
                                               w2, b2_, g2, be2, stats0, stats1, stats2,
                                               out_points);
}